// Round 15
// baseline (650.784 us; speedup 1.0000x reference)
//
#include <hip/hip_runtime.h>

#define S_LEN   2048
#define HID_DIM 4096
#define NHEADS  32
#define NKVH    8
#define HD      128
#define KV_DIM  1024
#define KV2     2048   // fused K|V row stride
#define BS_ROWS 4096   // B * S

typedef __attribute__((ext_vector_type(4))) float f32x4;
typedef __attribute__((ext_vector_type(8))) short bf16x8;

// ---------------- helpers ----------------
__device__ __forceinline__ unsigned short f2b(float f) {
  union { float f; unsigned int u; } cv; cv.f = f;
  unsigned int r = (cv.u + 0x7FFFu + ((cv.u >> 16) & 1u)) >> 16;  // RNE
  return (unsigned short)r;
}
__device__ __forceinline__ float b2f(unsigned short u) {
  union { unsigned int u; float f; } cv; cv.u = ((unsigned int)u) << 16; return cv.f;
}
__device__ __forceinline__ void gload_lds16(const void* g, void* l) {
  __builtin_amdgcn_global_load_lds(
      (const __attribute__((address_space(1))) unsigned int*)g,
      (__attribute__((address_space(3))) unsigned int*)l, 16, 0, 0);
}
__device__ __forceinline__ float exp2fast(float x) {
#if __has_builtin(__builtin_amdgcn_exp2f)
  return __builtin_amdgcn_exp2f(x);
#else
  return exp2f(x);
#endif
}
__device__ __forceinline__ unsigned cvtpk(float a, float b) {
  unsigned r;
  asm("v_cvt_pk_bf16_f32 %0, %1, %2" : "=v"(r) : "v"(a), "v"(b));
  return r;
}
__device__ __forceinline__ void store_out(float* p, float v) { *p = v; }
__device__ __forceinline__ void store_out(unsigned short* p, float v) { *p = f2b(v); }

// ---------------- fused prep: cvt(x) + transpose(Wq,Wk,Wv) + rope tables ----------
// block ranges: [0,16384) cvt | [16384,32768) tWq | [32768,36864) tWk |
//               [36864,40960) tWv | [40960,41472) rope tables
__global__ __launch_bounds__(256) void prep_k(const float* __restrict__ x,
                                              unsigned short* __restrict__ xb,
                                              const float* __restrict__ Wq,
                                              unsigned short* __restrict__ wtq,
                                              const float* __restrict__ Wk,
                                              unsigned short* __restrict__ wtk,
                                              const float* __restrict__ Wv,
                                              unsigned short* __restrict__ wtv,
                                              float* __restrict__ cosT,
                                              float* __restrict__ sinT) {
  __shared__ float t[32][33];
  int bid = blockIdx.x;
  const int tid = threadIdx.x;
  if (bid < 16384) {                       // ---- cvt x -> bf16 (exact grid)
    int i = bid * 256 + tid;
    f32x4 v = reinterpret_cast<const f32x4*>(x)[i];
    ushort4 o;
    o.x = f2b(v[0]); o.y = f2b(v[1]); o.z = f2b(v[2]); o.w = f2b(v[3]);
    reinterpret_cast<ushort4*>(xb)[i] = o;
    return;
  }
  bid -= 16384;
  const float* W; unsigned short* Wt; int Nd, bx, by;
  if (bid < 16384) { W = Wq; Wt = wtq; Nd = HID_DIM; bx = bid & 127; by = bid >> 7; }
  else {
    bid -= 16384;
    if (bid < 4096) { W = Wk; Wt = wtk; Nd = KV_DIM; bx = bid & 31; by = bid >> 5; }
    else {
      bid -= 4096;
      if (bid < 4096) { W = Wv; Wt = wtv; Nd = KV_DIM; bx = bid & 31; by = bid >> 5; }
      else {                               // ---- rope tables (exact grid)
        bid -= 4096;
        int idx = bid * 256 + tid;         // < S_LEN*64
        int s = idx >> 6, i = idx & 63;
        float inv = 1.0f / powf(10000.0f, (float)(2 * i) * (1.0f / 128.0f));
        float ang = (float)s * inv;
        cosT[idx] = cosf(ang);
        sinT[idx] = sinf(ang);
        return;
      }
    }
  }
  // ---- transpose+convert tile (proven body; tx=tid&31, ty=tid>>5)
  const int tx = tid & 31, ty = tid >> 5;
  const int n0 = bx * 32, k0 = by * 32;
#pragma unroll
  for (int i = 0; i < 4; ++i)
    t[ty + 8 * i][tx] = W[(size_t)(k0 + ty + 8 * i) * Nd + n0 + tx];
  __syncthreads();
#pragma unroll
  for (int i = 0; i < 4; ++i)
    Wt[(size_t)(n0 + ty + 8 * i) * HID_DIM + k0 + tx] = f2b(t[tx][ty + 8 * i]);
}

// ---------------- fused post-KV: K-RoPE + V transpose + Wo transpose ----------------
// block ranges: [0,2048) ropeK | [2048,6144) transpose_v | [6144,22528) transpose_Wo
__global__ __launch_bounds__(256) void postkv_k(unsigned short* __restrict__ KVb,
                                                unsigned short* __restrict__ Vt,
                                                const float* __restrict__ Wo,
                                                unsigned short* __restrict__ woT,
                                                const float* __restrict__ cosT,
                                                const float* __restrict__ sinT) {
  __shared__ float tf[32][33];
  __shared__ unsigned short tsh[32][33];
  int bid = blockIdx.x;
  const int tid = threadIdx.x;
  if (bid < 2048) {                        // ---- RoPE on K half (4 pairs/thread)
    int idx = bid * 256 + tid;             // < BS_ROWS*NKVH*16
    int i4 = idx & 15;
    int t = idx >> 4;
    int h = t & (NKVH - 1);
    int row = t >> 3;                      // t / NKVH
    int s = row & (S_LEN - 1);
    f32x4 c4 = *reinterpret_cast<const f32x4*>(&cosT[(s << 6) + i4 * 4]);
    f32x4 s4 = *reinterpret_cast<const f32x4*>(&sinT[(s << 6) + i4 * 4]);
    size_t base = (size_t)row * KV2 + (size_t)h * HD + i4 * 4;
    ushort4 xa = *reinterpret_cast<const ushort4*>(&KVb[base]);
    ushort4 xb2 = *reinterpret_cast<const ushort4*>(&KVb[base + 64]);
    unsigned short* pa = (unsigned short*)&xa;
    unsigned short* pb = (unsigned short*)&xb2;
    ushort4 oa, ob;
    unsigned short* qa = (unsigned short*)&oa;
    unsigned short* qb = (unsigned short*)&ob;
#pragma unroll
    for (int j = 0; j < 4; ++j) {
      float x1 = b2f(pa[j]), x2 = b2f(pb[j]);
      qa[j] = f2b(x1 * c4[j] - x2 * s4[j]);
      qb[j] = f2b(x2 * c4[j] + x1 * s4[j]);
    }
    *reinterpret_cast<ushort4*>(&KVb[base])      = oa;
    *reinterpret_cast<ushort4*>(&KVb[base + 64]) = ob;
    return;
  }
  bid -= 2048;
  const int tx = tid & 31, ty = tid >> 5;
  if (bid < 4096) {                        // ---- V transpose (proven body, strided src)
    int c0 = (bid & 31) * 32;              // col base 0..1023 (within V half)
    int r0 = (bid >> 5) * 32;              // row base 0..4095
#pragma unroll
    for (int i = 0; i < 4; ++i)
      tsh[ty + 8 * i][tx] = KVb[(size_t)(r0 + ty + 8 * i) * KV2 + KV_DIM + c0 + tx];
    __syncthreads();
    int ob2 = (r0 >> 11) * 1024;           // b * (8 kvh * 128 d)
    int oc = r0 & 2047;                    // s base
#pragma unroll
    for (int i = 0; i < 4; ++i)
      Vt[(size_t)(ob2 + c0 + ty + 8 * i) * S_LEN + oc + tx] = tsh[tx][ty + 8 * i];
    return;
  }
  bid -= 4096;                             // ---- Wo transpose+convert (proven body)
  {
    int n0 = (bid & 127) * 32, k0 = (bid >> 7) * 32;
#pragma unroll
    for (int i = 0; i < 4; ++i)
      tf[ty + 8 * i][tx] = Wo[(size_t)(k0 + ty + 8 * i) * HID_DIM + n0 + tx];
    __syncthreads();
#pragma unroll
    for (int i = 0; i < 4; ++i)
      woT[(size_t)(n0 + ty + 8 * i) * HID_DIM + k0 + tx] = f2b(tf[tx][ty + 8 * i]);
  }
}

// ---------------- 128-tile bf16 MFMA GEMM (m97 structure) — KV proj ----------
template <typename OutT>
__global__ __launch_bounds__(256) void gemm_bt(const unsigned short* __restrict__ A,
                                               const unsigned short* __restrict__ Bt,
                                               OutT* __restrict__ C, int M, int N, int K) {
  __shared__ unsigned short As[128 * 32];
  __shared__ unsigned short Bs[128 * 32];
  const int tid = threadIdx.x;
  const int lane = tid & 63;
  const int wave = tid >> 6;
  int nwg = gridDim.x, wg = blockIdx.x;
  int swz = (nwg % 8 == 0) ? ((wg & 7) * (nwg >> 3) + (wg >> 3)) : wg;
  const int nbn = N >> 7;
  const int bm = swz / nbn, bn = swz % nbn;
  const int m0 = bm << 7, n0 = bn << 7;
  const int wr = wave >> 1, wc = wave & 1;
  const int lr = lane & 15, kb = lane >> 4;

  f32x4 acc[4][4];
#pragma unroll
  for (int i = 0; i < 4; ++i)
#pragma unroll
    for (int j = 0; j < 4; ++j) acc[i][j] = (f32x4){0.f, 0.f, 0.f, 0.f};

  const unsigned short* Ab = A + (size_t)m0 * K;
  const unsigned short* Bb = Bt + (size_t)n0 * K;

  for (int k0 = 0; k0 < K; k0 += 32) {
    __syncthreads();
#pragma unroll
    for (int i = 0; i < 2; ++i) {
      int idx = i * 256 + tid;
      int row = idx >> 2;
      int off = (idx & 3) << 3;
      gload_lds16(Ab + (size_t)row * K + k0 + off, As + row * 32 + off);
      gload_lds16(Bb + (size_t)row * K + k0 + off, Bs + row * 32 + off);
    }
    __syncthreads();

    bf16x8 af[4], bfr[4];
#pragma unroll
    for (int mi = 0; mi < 4; ++mi)
      af[mi] = *reinterpret_cast<const bf16x8*>(As + (wr * 64 + mi * 16 + lr) * 32 + kb * 8);
#pragma unroll
    for (int ni = 0; ni < 4; ++ni)
      bfr[ni] = *reinterpret_cast<const bf16x8*>(Bs + (wc * 64 + ni * 16 + lr) * 32 + kb * 8);
#pragma unroll
    for (int mi = 0; mi < 4; ++mi)
#pragma unroll
      for (int ni = 0; ni < 4; ++ni)
        acc[mi][ni] = __builtin_amdgcn_mfma_f32_16x16x32_bf16(af[mi], bfr[ni], acc[mi][ni], 0, 0, 0);
  }

#pragma unroll
  for (int mi = 0; mi < 4; ++mi)
#pragma unroll
    for (int ni = 0; ni < 4; ++ni)
#pragma unroll
      for (int r = 0; r < 4; ++r) {
        int row = m0 + wr * 64 + mi * 16 + kb * 4 + r;
        int col = n0 + wc * 64 + ni * 16 + lr;
        store_out(&C[(size_t)row * N + col], acc[mi][ni][r]);
      }
}

// ---------------- 256-tile 8-wave 4-phase GEMM (T2+T3+T4+T5) — Q/O proj ----------
#define STAGE_HALF(dstBase, Sp, k0, h)                                           \
  {                                                                              \
    _Pragma("unroll")                                                            \
    for (int i_ = 0; i_ < 2; ++i_) {                                             \
      int c_ = i_ * 512 + tid;                                                   \
      int rl_ = c_ >> 3, ch_ = c_ & 7;                                           \
      int row_ = (h) * 128 + rl_;                                                \
      gload_lds16((Sp) + (size_t)row_ * K + (k0) + ((ch_ ^ (row_ & 7)) << 3),    \
                  (char*)(dstBase) + row_ * 128 + ch_ * 16);                     \
    }                                                                            \
  }
#define LDF(buf, R, sw) \
  (*reinterpret_cast<const bf16x8*>((const char*)(buf) + (R) * 128 + (sw)))
#define PHASE_SYNC()                                        \
  __builtin_amdgcn_s_barrier();                             \
  asm volatile("s_waitcnt lgkmcnt(0)" ::: "memory");        \
  __builtin_amdgcn_sched_barrier(0);

template <typename OutT>
__global__ __launch_bounds__(512, 1) void gemm256(const unsigned short* __restrict__ A,
                                                  const unsigned short* __restrict__ Bt,
                                                  OutT* __restrict__ C, int M, int N, int K) {
  __shared__ unsigned short Asl[2][256 * 64];
  __shared__ unsigned short Bsl[2][256 * 64];
  const int tid = threadIdx.x;
  const int lane = tid & 63;
  const int wave = tid >> 6;       // 0..7
  const int wr = wave >> 2;        // 0..1  (M)
  const int wc = wave & 3;         // 0..3  (N)
  const int lr = lane & 15, kb = lane >> 4;

  int nwg = gridDim.x, wg = blockIdx.x;
  int swz = (nwg % 8 == 0) ? ((wg & 7) * (nwg >> 3) + (wg >> 3)) : wg;
  const int nbn = N >> 8;
  const int bm = swz / nbn, bn = swz % nbn;
  const int m0 = bm << 8, n0 = bn << 8;

  const unsigned short* Ab = A + (size_t)m0 * K;
  const unsigned short* Bb = Bt + (size_t)n0 * K;

  f32x4 acc[8][4];
#pragma unroll
  for (int i = 0; i < 8; ++i)
#pragma unroll
    for (int j = 0; j < 4; ++j) acc[i][j] = (f32x4){0.f, 0.f, 0.f, 0.f};

  const int sw0 = ((kb) ^ (lr & 7)) << 4;
  const int sw1 = ((4 + kb) ^ (lr & 7)) << 4;

  STAGE_HALF(Asl[0], Ab, 0, 0); STAGE_HALF(Asl[0], Ab, 0, 1);
  STAGE_HALF(Bsl[0], Bb, 0, 0); STAGE_HALF(Bsl[0], Bb, 0, 1);
  __syncthreads();

  const int nt = K >> 6;
  bf16x8 af[4], bfr[4];

#pragma unroll 1
  for (int t = 0; t < nt; ++t) {
    const unsigned short* Acur = Asl[t & 1];
    const unsigned short* Bcur = Bsl[t & 1];
    unsigned short* Anxt = Asl[(t + 1) & 1];
    unsigned short* Bnxt = Bsl[(t + 1) & 1];
    const int k0n = (t + 1) << 6;
    const bool pf = (t + 1 < nt);

    // ---- phase 0: (mh=0, kk=0); stage A(t+1)
#pragma unroll
    for (int ni = 0; ni < 4; ++ni) bfr[ni] = LDF(Bcur, wc * 64 + ni * 16 + lr, sw0);
#pragma unroll
    for (int mi = 0; mi < 4; ++mi) af[mi] = LDF(Acur, wr * 128 + mi * 16 + lr, sw0);
    if (pf) { STAGE_HALF(Anxt, Ab, k0n, 0); STAGE_HALF(Anxt, Ab, k0n, 1); }
    PHASE_SYNC();
    __builtin_amdgcn_s_setprio(1);
#pragma unroll
    for (int mi = 0; mi < 4; ++mi)
#pragma unroll
      for (int ni = 0; ni < 4; ++ni)
        acc[mi][ni] = __builtin_amdgcn_mfma_f32_16x16x32_bf16(af[mi], bfr[ni], acc[mi][ni], 0, 0, 0);
    __builtin_amdgcn_s_setprio(0);
    __builtin_amdgcn_s_barrier();

    // ---- phase 1: (mh=1, kk=0); stage B(t+1)
#pragma unroll
    for (int mi = 0; mi < 4; ++mi) af[mi] = LDF(Acur, wr * 128 + (mi + 4) * 16 + lr, sw0);
    if (pf) { STAGE_HALF(Bnxt, Bb, k0n, 0); STAGE_HALF(Bnxt, Bb, k0n, 1); }
    PHASE_SYNC();
    __builtin_amdgcn_s_setprio(1);
#pragma unroll
    for (int mi = 0; mi < 4; ++mi)
#pragma unroll
      for (int ni = 0; ni < 4; ++ni)
        acc[mi + 4][ni] = __builtin_amdgcn_mfma_f32_16x16x32_bf16(af[mi], bfr[ni], acc[mi + 4][ni], 0, 0, 0);
    __builtin_amdgcn_s_setprio(0);
    __builtin_amdgcn_s_barrier();

    // ---- phase 2: (mh=0, kk=1)
#pragma unroll
    for (int ni = 0; ni < 4; ++ni) bfr[ni] = LDF(Bcur, wc * 64 + ni * 16 + lr, sw1);
#pragma unroll
    for (int mi = 0; mi < 4; ++mi) af[mi] = LDF(Acur, wr * 128 + mi * 16 + lr, sw1);
    PHASE_SYNC();
    __builtin_amdgcn_s_setprio(1);
#pragma unroll
    for (int mi = 0; mi < 4; ++mi)
#pragma unroll
      for (int ni = 0; ni < 4; ++ni)
        acc[mi][ni] = __builtin_amdgcn_mfma_f32_16x16x32_bf16(af[mi], bfr[ni], acc[mi][ni], 0, 0, 0);
    __builtin_amdgcn_s_setprio(0);
    __builtin_amdgcn_s_barrier();

    // ---- phase 3: (mh=1, kk=1)
#pragma unroll
    for (int mi = 0; mi < 4; ++mi) af[mi] = LDF(Acur, wr * 128 + (mi + 4) * 16 + lr, sw1);
    PHASE_SYNC();
    __builtin_amdgcn_s_setprio(1);
#pragma unroll
    for (int mi = 0; mi < 4; ++mi)
#pragma unroll
      for (int ni = 0; ni < 4; ++ni)
        acc[mi + 4][ni] = __builtin_amdgcn_mfma_f32_16x16x32_bf16(af[mi], bfr[ni], acc[mi + 4][ni], 0, 0, 0);
    __builtin_amdgcn_s_setprio(0);
    __builtin_amdgcn_s_barrier();

    if (pf) asm volatile("s_waitcnt vmcnt(0)" ::: "memory");
    __builtin_amdgcn_s_barrier();
  }

#pragma unroll
  for (int mi = 0; mi < 8; ++mi)
#pragma unroll
    for (int ni = 0; ni < 4; ++ni)
#pragma unroll
      for (int r = 0; r < 4; ++r) {
        int row = m0 + wr * 128 + mi * 16 + kb * 4 + r;
        int col = n0 + wc * 64 + ni * 16 + lr;
        store_out(&C[(size_t)row * N + col], acc[mi][ni][r]);
      }
}

// ---------------- flash attention (causal, GQA 32/8, D=128) ----------------
// r11-proven body; UNPAIRED grid (16,64), one q-tile per block, longest-first
// (qt = 15 - bx, LPT). LDS 50KB -> 3 blocks/CU resident (occupancy lever).
__global__ __launch_bounds__(256, 2) void attn_fwd(const unsigned short* __restrict__ Q,
                                                   const unsigned short* __restrict__ KV,
                                                   const unsigned short* __restrict__ Vt,
                                                   const float* __restrict__ cosT,
                                                   const float* __restrict__ sinT,
                                                   unsigned short* __restrict__ O) {
  __shared__ unsigned short Ks[2][64 * 128];   // 32 KB (double buffer)
  __shared__ unsigned short Ps[4][2][16 * 72]; // 18.4 KB
  const int tid = threadIdx.x, lane = tid & 63, wave = tid >> 6;
  const int lr = lane & 15, kb = lane >> 4;
  const int bh = blockIdx.y;           // 0..63
  const int b = bh >> 5, h = bh & 31, kvh = h >> 2;
  const unsigned short* Qp = Q + (size_t)b * S_LEN * HID_DIM + (size_t)h * HD;
  const unsigned short* Kp = KV + (size_t)b * S_LEN * KV2 + (size_t)kvh * HD;
  const unsigned short* Vtp = Vt + (size_t)(b * 8 + kvh) * HD * S_LEN;  // [128][2048]
  unsigned short* Op = O + (size_t)b * S_LEN * HID_DIM + (size_t)h * HD;

  const int qt = 15 - blockIdx.x;      // longest blocks dispatched first (LPT)
  const int q0 = qt * 128;
  int qrowQ[2];
  qrowQ[0] = q0 + wave * 32 + lr;
  qrowQ[1] = q0 + wave * 32 + 16 + lr;

  // ---- load raw Q + fused RoPE + scale (1/sqrt(128) * log2e folded) ----
  bf16x8 qf[2][4];
#pragma unroll
  for (int qs = 0; qs < 2; ++qs) {
    const int qrow = qrowQ[qs];
    bf16x8 raw[4];
#pragma unroll
    for (int dc = 0; dc < 4; ++dc)
      raw[dc] = *reinterpret_cast<const bf16x8*>(Qp + (size_t)qrow * HID_DIM + dc * 32 + kb * 8);
    const float* ct = cosT + (qrow << 6) + kb * 8;
    const float* st = sinT + (qrow << 6) + kb * 8;
    f32x4 cv0 = *(const f32x4*)(ct),      cv1 = *(const f32x4*)(ct + 4);
    f32x4 cv2 = *(const f32x4*)(ct + 32), cv3 = *(const f32x4*)(ct + 36);
    f32x4 sv0 = *(const f32x4*)(st),      sv1 = *(const f32x4*)(st + 4);
    f32x4 sv2 = *(const f32x4*)(st + 32), sv3 = *(const f32x4*)(st + 36);
    const float sc = 0.08838834764831843f * 1.4426950408889634f;  // 1/sqrt(128) * log2(e)
#pragma unroll
    for (int j = 0; j < 8; ++j) {
      const int jj = j & 3;
      float c0 = (j < 4) ? cv0[jj] : cv1[jj];
      float s0 = (j < 4) ? sv0[jj] : sv1[jj];
      float c1 = (j < 4) ? cv2[jj] : cv3[jj];
      float s1 = (j < 4) ? sv2[jj] : sv3[jj];
      float a1 = b2f((unsigned short)raw[0][j]), a2 = b2f((unsigned short)raw[2][j]);
      qf[qs][0][j] = (short)f2b((a1 * c0 - a2 * s0) * sc);
      qf[qs][2][j] = (short)f2b((a2 * c0 + a1 * s0) * sc);
      float b1 = b2f((unsigned short)raw[1][j]), b2x = b2f((unsigned short)raw[3][j]);
      qf[qs][1][j] = (short)f2b((b1 * c1 - b2x * s1) * sc);
      qf[qs][3][j] = (short)f2b((b2x * c1 + b1 * s1) * sc);
    }
  }

  f32x4 of[2][8];
#pragma unroll
  for (int qs = 0; qs < 2; ++qs)
#pragma unroll
    for (int i = 0; i < 8; ++i) of[qs][i] = (f32x4){0.f, 0.f, 0.f, 0.f};
  float mrow[2] = {-3.0e38f, -3.0e38f};
  float lrow[2] = {0.f, 0.f};

  const int nsteps = 2 * qt + 2;       // 64-key steps covering q0+128 keys

  // ---- prologue: stage tile 0 into Ks[0]
#pragma unroll
  for (int i = 0; i < 4; ++i) {
    int c = i * 256 + tid;
    int key = c >> 4;
    int ch = (c & 15) ^ (key & 7);
    gload_lds16(Kp + (size_t)key * KV2 + ch * 8, &Ks[0][0] + c * 8);
  }
  __syncthreads();   // tile 0 visible

#pragma unroll 1
  for (int t = 0; t < nsteps; ++t) {
    const int kv0 = t << 6;
    const unsigned short* Kcur = &Ks[t & 1][0];

    // --- V group-0 loads FIRST (PV0 waits only these; prefetch stays in flight)
    bf16x8 vf[8];
#pragma unroll
    for (int dc2 = 0; dc2 < 8; ++dc2)
      vf[dc2] = *reinterpret_cast<const bf16x8*>(
          Vtp + (size_t)(dc2 * 16 + lr) * S_LEN + kv0 + kb * 8);

    // --- prefetch next K tile (drained only at step-end barrier)
    if (t + 1 < nsteps) {
      unsigned short* Knxt = &Ks[(t + 1) & 1][0];
#pragma unroll
      for (int i = 0; i < 4; ++i) {
        int c = i * 256 + tid;
        int key = c >> 4;
        int ch = (c & 15) ^ (key & 7);
        gload_lds16(Kp + (size_t)(kv0 + 64 + key) * KV2 + ch * 8, Knxt + c * 8);
      }
    }

    // --- S^T = K Q^T : kf shared across q-sets
    f32x4 sf[2][4];
#pragma unroll
    for (int qs = 0; qs < 2; ++qs)
#pragma unroll
      for (int ki = 0; ki < 4; ++ki) sf[qs][ki] = (f32x4){0.f, 0.f, 0.f, 0.f};
#pragma unroll
    for (int ki = 0; ki < 4; ++ki)
#pragma unroll
      for (int dc = 0; dc < 4; ++dc) {
        bf16x8 kf = *reinterpret_cast<const bf16x8*>(
            Kcur + (ki * 16 + lr) * 128 + (((dc * 4 + kb) ^ (lr & 7)) << 3));
        sf[0][ki] = __builtin_amdgcn_mfma_f32_16x16x32_bf16(kf, qf[0][dc], sf[0][ki], 0, 0, 0);
        sf[1][ki] = __builtin_amdgcn_mfma_f32_16x16x32_bf16(kf, qf[1][dc], sf[1][ki], 0, 0, 0);
      }

    // --- causal mask per q-set (wave-uniform skip)
#pragma unroll
    for (int qs = 0; qs < 2; ++qs) {
      if (kv0 + 63 > q0 + wave * 32 + qs * 16) {
        const int thr = qrowQ[qs] - kv0;
#pragma unroll
        for (int ki = 0; ki < 4; ++ki)
#pragma unroll
          for (int r = 0; r < 4; ++r)
            if (ki * 16 + kb * 4 + r > thr) sf[qs][ki][r] = -3.0e38f;
      }
    }

    // --- two independent softmax chains (log2 domain), defer-max THR=11.5 bits
#pragma unroll
    for (int qs = 0; qs < 2; ++qs) {
      float m8 = -3.0e38f;
#pragma unroll
      for (int ki = 0; ki < 4; ++ki)
#pragma unroll
        for (int r = 0; r < 4; ++r) m8 = fmaxf(m8, sf[qs][ki][r]);
      m8 = fmaxf(m8, __shfl_xor(m8, 16));
      m8 = fmaxf(m8, __shfl_xor(m8, 32));
      if (__any(m8 > mrow[qs] + 11.5f)) {
        float mn = fmaxf(mrow[qs], m8);
        float corr = exp2fast(mrow[qs] - mn);
        lrow[qs] *= corr;
#pragma unroll
        for (int r = 0; r < 4; ++r) {
          float cr = __shfl(corr, kb * 4 + r);
#pragma unroll
          for (int dc2 = 0; dc2 < 8; ++dc2) of[qs][dc2][r] *= cr;
        }
        mrow[qs] = mn;
      }
      float rs = 0.f;
#pragma unroll
      for (int ki = 0; ki < 4; ++ki) {
        float p0 = exp2fast(sf[qs][ki][0] - mrow[qs]);   // bounded by 2^11.5
        float p1 = exp2fast(sf[qs][ki][1] - mrow[qs]);
        float p2 = exp2fast(sf[qs][ki][2] - mrow[qs]);
        float p3 = exp2fast(sf[qs][ki][3] - mrow[qs]);
        rs += (p0 + p1) + (p2 + p3);
        uint2 w;
        w.x = cvtpk(p0, p1);
        w.y = cvtpk(p2, p3);
        *reinterpret_cast<uint2*>(&Ps[wave][qs][lr * 72 + ki * 16 + kb * 4]) = w;
      }
      rs += __shfl_xor(rs, 16);
      rs += __shfl_xor(rs, 32);
      lrow[qs] += rs;
    }
    asm volatile("s_waitcnt lgkmcnt(0)" ::: "memory");
    __builtin_amdgcn_sched_barrier(0);

    // --- PV group 0 (keys kv0..+31), both q-sets share vf
    {
      bf16x8 pf0 = *reinterpret_cast<const bf16x8*>(&Ps[wave][0][lr * 72 + kb * 8]);
      bf16x8 pf1 = *reinterpret_cast<const bf16x8*>(&Ps[wave][1][lr * 72 + kb * 8]);
#pragma unroll
      for (int dc2 = 0; dc2 < 8; ++dc2) {
        of[0][dc2] = __builtin_amdgcn_mfma_f32_16x16x32_bf16(pf0, vf[dc2], of[0][dc2], 0, 0, 0);
        of[1][dc2] = __builtin_amdgcn_mfma_f32_16x16x32_bf16(pf1, vf[dc2], of[1][dc2], 0, 0, 0);
      }
    }
    // --- V group 1 + PV group 1
#pragma unroll
    for (int dc2 = 0; dc2 < 8; ++dc2)
      vf[dc2] = *reinterpret_cast<const bf16x8*>(
          Vtp + (size_t)(dc2 * 16 + lr) * S_LEN + kv0 + 32 + kb * 8);
    {
      bf16x8 pf0 = *reinterpret_cast<const bf16x8*>(&Ps[wave][0][lr * 72 + 32 + kb * 8]);
      bf16x8 pf1 = *reinterpret_cast<const bf16x8*>(&Ps[wave][1][lr * 72 + 32 + kb * 8]);
#pragma unroll
      for (int dc2 = 0; dc2 < 8; ++dc2) {
        of[0][dc2] = __builtin_amdgcn_mfma_f32_16x16x32_bf16(pf0, vf[dc2], of[0][dc2], 0, 0, 0);
        of[1][dc2] = __builtin_amdgcn_mfma_f32_16x16x32_bf16(pf1, vf[dc2], of[1][dc2], 0, 0, 0);
      }
    }

    __syncthreads();  // one drain/step: prefetch resident; all Kcur reads done
  }

  // --- normalize + write (of[qs] row q = kb*4+r; lrow lives at lane lr = q)
#pragma unroll
  for (int qs = 0; qs < 2; ++qs) {
    float linv[4];
#pragma unroll
    for (int r = 0; r < 4; ++r) linv[r] = 1.0f / __shfl(lrow[qs], kb * 4 + r);
#pragma unroll
    for (int dc2 = 0; dc2 < 8; ++dc2)
#pragma unroll
      for (int r = 0; r < 4; ++r) {
        int qg = q0 + wave * 32 + qs * 16 + kb * 4 + r;
        Op[(size_t)qg * HID_DIM + dc2 * 16 + lr] = f2b(of[qs][dc2][r] * linv[r]);
      }
  }
}

// ---------------- launch ----------------
extern "C" void kernel_launch(void* const* d_in, const int* in_sizes, int n_in,
                              void* d_out, int out_size, void* d_ws, size_t ws_size,
                              hipStream_t stream) {
  const float* x  = (const float*)d_in[0];
  const float* Wq = (const float*)d_in[2];
  const float* Wk = (const float*)d_in[3];
  const float* Wv = (const float*)d_in[4];
  const float* Wo = (const float*)d_in[5];
  float* out = (float*)d_out;

  char* ws = (char*)d_ws;
  unsigned short* xb  = (unsigned short*)(ws + 0);          // 33.5MB (later reused as AO)
  unsigned short* wtb = (unsigned short*)(ws + 33554432);   // Wq^T; later Wo^T
  unsigned short* wkt = (unsigned short*)(ws + 67108864);   // Wk^T | Wv^T contiguous; later Vt
  unsigned short* wvt = (unsigned short*)(ws + 75497472);
  unsigned short* Qb  = (unsigned short*)(ws + 83886080);
  unsigned short* KVb = (unsigned short*)(ws + 117440512);  // [4096][2048] fused K|V
  float* cosT = (float*)(ws + 134217728);
  float* sinT = (float*)(ws + 134742016);
  unsigned short* AO  = xb;   // alias: x dead after KV projection
  unsigned short* Vtb = wkt;  // alias: Wk^T/Wv^T dead after KV projection
  unsigned short* woT = wtb;  // alias: Wq^T dead after Q projection

  prep_k<<<41472, 256, 0, stream>>>(x, xb, Wq, wtb, Wk, wkt, Wv, wvt, cosT, sinT);

  gemm256<unsigned short><<<256, 512, 0, stream>>>(xb, wtb, Qb, BS_ROWS, HID_DIM, HID_DIM);  // raw Q
  gemm_bt<unsigned short><<<512, 256, 0, stream>>>(xb, wkt, KVb, BS_ROWS, KV2, HID_DIM);     // fused K|V

  // K-RoPE + V transpose + Wo transpose (wkt/wtb regions now dead -> Vt/woT)
  postkv_k<<<22528, 256, 0, stream>>>(KVb, Vtb, Wo, woT, cosT, sinT);

  attn_fwd<<<dim3(16, 64), 256, 0, stream>>>(Qb, KVb, Vtb, cosT, sinT, AO);

  gemm256<float><<<256, 512, 0, stream>>>(AO, woT, out, BS_ROWS, HID_DIM, HID_DIM);
}

// Round 16
// 543.325 us; speedup vs baseline: 1.1978x; 1.1978x over previous
//
#include <hip/hip_runtime.h>

#define S_LEN   2048
#define HID_DIM 4096
#define NHEADS  32
#define NKVH    8
#define HD      128
#define KV_DIM  1024
#define KV2     2048   // fused K|V row stride
#define BS_ROWS 4096   // B * S

typedef __attribute__((ext_vector_type(4))) float f32x4;
typedef __attribute__((ext_vector_type(8))) short bf16x8;

// ---------------- helpers ----------------
__device__ __forceinline__ unsigned short f2b(float f) {
  union { float f; unsigned int u; } cv; cv.f = f;
  unsigned int r = (cv.u + 0x7FFFu + ((cv.u >> 16) & 1u)) >> 16;  // RNE
  return (unsigned short)r;
}
__device__ __forceinline__ float b2f(unsigned short u) {
  union { unsigned int u; float f; } cv; cv.u = ((unsigned int)u) << 16; return cv.f;
}
__device__ __forceinline__ void gload_lds16(const void* g, void* l) {
  __builtin_amdgcn_global_load_lds(
      (const __attribute__((address_space(1))) unsigned int*)g,
      (__attribute__((address_space(3))) unsigned int*)l, 16, 0, 0);
}
__device__ __forceinline__ float exp2fast(float x) {
#if __has_builtin(__builtin_amdgcn_exp2f)
  return __builtin_amdgcn_exp2f(x);
#else
  return exp2f(x);
#endif
}
__device__ __forceinline__ unsigned cvtpk(float a, float b) {
  unsigned r;
  asm("v_cvt_pk_bf16_f32 %0, %1, %2" : "=v"(r) : "v"(a), "v"(b));
  return r;
}
__device__ __forceinline__ void store_out(float* p, float v) { *p = v; }
__device__ __forceinline__ void store_out(unsigned short* p, float v) { *p = f2b(v); }

// ---------------- fused prep: cvt(x) + transpose(Wq,Wk,Wv) + rope tables ----------
// block ranges: [0,16384) cvt | [16384,32768) tWq | [32768,36864) tWk |
//               [36864,40960) tWv | [40960,41472) rope tables
__global__ __launch_bounds__(256) void prep_k(const float* __restrict__ x,
                                              unsigned short* __restrict__ xb,
                                              const float* __restrict__ Wq,
                                              unsigned short* __restrict__ wtq,
                                              const float* __restrict__ Wk,
                                              unsigned short* __restrict__ wtk,
                                              const float* __restrict__ Wv,
                                              unsigned short* __restrict__ wtv,
                                              float* __restrict__ cosT,
                                              float* __restrict__ sinT) {
  __shared__ float t[32][33];
  int bid = blockIdx.x;
  const int tid = threadIdx.x;
  if (bid < 16384) {                       // ---- cvt x -> bf16 (exact grid)
    int i = bid * 256 + tid;
    f32x4 v = reinterpret_cast<const f32x4*>(x)[i];
    ushort4 o;
    o.x = f2b(v[0]); o.y = f2b(v[1]); o.z = f2b(v[2]); o.w = f2b(v[3]);
    reinterpret_cast<ushort4*>(xb)[i] = o;
    return;
  }
  bid -= 16384;
  const float* W; unsigned short* Wt; int Nd, bx, by;
  if (bid < 16384) { W = Wq; Wt = wtq; Nd = HID_DIM; bx = bid & 127; by = bid >> 7; }
  else {
    bid -= 16384;
    if (bid < 4096) { W = Wk; Wt = wtk; Nd = KV_DIM; bx = bid & 31; by = bid >> 5; }
    else {
      bid -= 4096;
      if (bid < 4096) { W = Wv; Wt = wtv; Nd = KV_DIM; bx = bid & 31; by = bid >> 5; }
      else {                               // ---- rope tables (exact grid)
        bid -= 4096;
        int idx = bid * 256 + tid;         // < S_LEN*64
        int s = idx >> 6, i = idx & 63;
        float inv = 1.0f / powf(10000.0f, (float)(2 * i) * (1.0f / 128.0f));
        float ang = (float)s * inv;
        cosT[idx] = cosf(ang);
        sinT[idx] = sinf(ang);
        return;
      }
    }
  }
  // ---- transpose+convert tile (proven body; tx=tid&31, ty=tid>>5)
  const int tx = tid & 31, ty = tid >> 5;
  const int n0 = bx * 32, k0 = by * 32;
#pragma unroll
  for (int i = 0; i < 4; ++i)
    t[ty + 8 * i][tx] = W[(size_t)(k0 + ty + 8 * i) * Nd + n0 + tx];
  __syncthreads();
#pragma unroll
  for (int i = 0; i < 4; ++i)
    Wt[(size_t)(n0 + ty + 8 * i) * HID_DIM + k0 + tx] = f2b(t[tx][ty + 8 * i]);
}

// ---------------- fused post-KV: K-RoPE + V transpose + Wo transpose ----------------
// block ranges: [0,2048) ropeK | [2048,6144) transpose_v | [6144,22528) transpose_Wo
__global__ __launch_bounds__(256) void postkv_k(unsigned short* __restrict__ KVb,
                                                unsigned short* __restrict__ Vt,
                                                const float* __restrict__ Wo,
                                                unsigned short* __restrict__ woT,
                                                const float* __restrict__ cosT,
                                                const float* __restrict__ sinT) {
  __shared__ float tf[32][33];
  __shared__ unsigned short tsh[32][33];
  int bid = blockIdx.x;
  const int tid = threadIdx.x;
  if (bid < 2048) {                        // ---- RoPE on K half (4 pairs/thread)
    int idx = bid * 256 + tid;             // < BS_ROWS*NKVH*16
    int i4 = idx & 15;
    int t = idx >> 4;
    int h = t & (NKVH - 1);
    int row = t >> 3;                      // t / NKVH
    int s = row & (S_LEN - 1);
    f32x4 c4 = *reinterpret_cast<const f32x4*>(&cosT[(s << 6) + i4 * 4]);
    f32x4 s4 = *reinterpret_cast<const f32x4*>(&sinT[(s << 6) + i4 * 4]);
    size_t base = (size_t)row * KV2 + (size_t)h * HD + i4 * 4;
    ushort4 xa = *reinterpret_cast<const ushort4*>(&KVb[base]);
    ushort4 xb2 = *reinterpret_cast<const ushort4*>(&KVb[base + 64]);
    unsigned short* pa = (unsigned short*)&xa;
    unsigned short* pb = (unsigned short*)&xb2;
    ushort4 oa, ob;
    unsigned short* qa = (unsigned short*)&oa;
    unsigned short* qb = (unsigned short*)&ob;
#pragma unroll
    for (int j = 0; j < 4; ++j) {
      float x1 = b2f(pa[j]), x2 = b2f(pb[j]);
      qa[j] = f2b(x1 * c4[j] - x2 * s4[j]);
      qb[j] = f2b(x2 * c4[j] + x1 * s4[j]);
    }
    *reinterpret_cast<ushort4*>(&KVb[base])      = oa;
    *reinterpret_cast<ushort4*>(&KVb[base + 64]) = ob;
    return;
  }
  bid -= 2048;
  const int tx = tid & 31, ty = tid >> 5;
  if (bid < 4096) {                        // ---- V transpose (proven body, strided src)
    int c0 = (bid & 31) * 32;              // col base 0..1023 (within V half)
    int r0 = (bid >> 5) * 32;              // row base 0..4095
#pragma unroll
    for (int i = 0; i < 4; ++i)
      tsh[ty + 8 * i][tx] = KVb[(size_t)(r0 + ty + 8 * i) * KV2 + KV_DIM + c0 + tx];
    __syncthreads();
    int ob2 = (r0 >> 11) * 1024;           // b * (8 kvh * 128 d)
    int oc = r0 & 2047;                    // s base
#pragma unroll
    for (int i = 0; i < 4; ++i)
      Vt[(size_t)(ob2 + c0 + ty + 8 * i) * S_LEN + oc + tx] = tsh[tx][ty + 8 * i];
    return;
  }
  bid -= 4096;                             // ---- Wo transpose+convert (proven body)
  {
    int n0 = (bid & 127) * 32, k0 = (bid >> 7) * 32;
#pragma unroll
    for (int i = 0; i < 4; ++i)
      tf[ty + 8 * i][tx] = Wo[(size_t)(k0 + ty + 8 * i) * HID_DIM + n0 + tx];
    __syncthreads();
#pragma unroll
    for (int i = 0; i < 4; ++i)
      woT[(size_t)(n0 + ty + 8 * i) * HID_DIM + k0 + tx] = f2b(tf[tx][ty + 8 * i]);
  }
}

// ---------------- 128-tile bf16 MFMA GEMM (m97 structure) — KV proj ----------
template <typename OutT>
__global__ __launch_bounds__(256) void gemm_bt(const unsigned short* __restrict__ A,
                                               const unsigned short* __restrict__ Bt,
                                               OutT* __restrict__ C, int M, int N, int K) {
  __shared__ unsigned short As[128 * 32];
  __shared__ unsigned short Bs[128 * 32];
  const int tid = threadIdx.x;
  const int lane = tid & 63;
  const int wave = tid >> 6;
  int nwg = gridDim.x, wg = blockIdx.x;
  int swz = (nwg % 8 == 0) ? ((wg & 7) * (nwg >> 3) + (wg >> 3)) : wg;
  const int nbn = N >> 7;
  const int bm = swz / nbn, bn = swz % nbn;
  const int m0 = bm << 7, n0 = bn << 7;
  const int wr = wave >> 1, wc = wave & 1;
  const int lr = lane & 15, kb = lane >> 4;

  f32x4 acc[4][4];
#pragma unroll
  for (int i = 0; i < 4; ++i)
#pragma unroll
    for (int j = 0; j < 4; ++j) acc[i][j] = (f32x4){0.f, 0.f, 0.f, 0.f};

  const unsigned short* Ab = A + (size_t)m0 * K;
  const unsigned short* Bb = Bt + (size_t)n0 * K;

  for (int k0 = 0; k0 < K; k0 += 32) {
    __syncthreads();
#pragma unroll
    for (int i = 0; i < 2; ++i) {
      int idx = i * 256 + tid;
      int row = idx >> 2;
      int off = (idx & 3) << 3;
      gload_lds16(Ab + (size_t)row * K + k0 + off, As + row * 32 + off);
      gload_lds16(Bb + (size_t)row * K + k0 + off, Bs + row * 32 + off);
    }
    __syncthreads();

    bf16x8 af[4], bfr[4];
#pragma unroll
    for (int mi = 0; mi < 4; ++mi)
      af[mi] = *reinterpret_cast<const bf16x8*>(As + (wr * 64 + mi * 16 + lr) * 32 + kb * 8);
#pragma unroll
    for (int ni = 0; ni < 4; ++ni)
      bfr[ni] = *reinterpret_cast<const bf16x8*>(Bs + (wc * 64 + ni * 16 + lr) * 32 + kb * 8);
#pragma unroll
    for (int mi = 0; mi < 4; ++mi)
#pragma unroll
      for (int ni = 0; ni < 4; ++ni)
        acc[mi][ni] = __builtin_amdgcn_mfma_f32_16x16x32_bf16(af[mi], bfr[ni], acc[mi][ni], 0, 0, 0);
  }

#pragma unroll
  for (int mi = 0; mi < 4; ++mi)
#pragma unroll
    for (int ni = 0; ni < 4; ++ni)
#pragma unroll
      for (int r = 0; r < 4; ++r) {
        int row = m0 + wr * 64 + mi * 16 + kb * 4 + r;
        int col = n0 + wc * 64 + ni * 16 + lr;
        store_out(&C[(size_t)row * N + col], acc[mi][ni][r]);
      }
}

// ---------------- 256-tile 8-wave 4-phase GEMM (T2+T3+T4+T5) — Q/O proj ----------
#define STAGE_HALF(dstBase, Sp, k0, h)                                           \
  {                                                                              \
    _Pragma("unroll")                                                            \
    for (int i_ = 0; i_ < 2; ++i_) {                                             \
      int c_ = i_ * 512 + tid;                                                   \
      int rl_ = c_ >> 3, ch_ = c_ & 7;                                           \
      int row_ = (h) * 128 + rl_;                                                \
      gload_lds16((Sp) + (size_t)row_ * K + (k0) + ((ch_ ^ (row_ & 7)) << 3),    \
                  (char*)(dstBase) + row_ * 128 + ch_ * 16);                     \
    }                                                                            \
  }
#define LDF(buf, R, sw) \
  (*reinterpret_cast<const bf16x8*>((const char*)(buf) + (R) * 128 + (sw)))
#define PHASE_SYNC()                                        \
  __builtin_amdgcn_s_barrier();                             \
  asm volatile("s_waitcnt lgkmcnt(0)" ::: "memory");        \
  __builtin_amdgcn_sched_barrier(0);

template <typename OutT>
__global__ __launch_bounds__(512, 1) void gemm256(const unsigned short* __restrict__ A,
                                                  const unsigned short* __restrict__ Bt,
                                                  OutT* __restrict__ C, int M, int N, int K) {
  __shared__ unsigned short Asl[2][256 * 64];
  __shared__ unsigned short Bsl[2][256 * 64];
  const int tid = threadIdx.x;
  const int lane = tid & 63;
  const int wave = tid >> 6;       // 0..7
  const int wr = wave >> 2;        // 0..1  (M)
  const int wc = wave & 3;         // 0..3  (N)
  const int lr = lane & 15, kb = lane >> 4;

  int nwg = gridDim.x, wg = blockIdx.x;
  int swz = (nwg % 8 == 0) ? ((wg & 7) * (nwg >> 3) + (wg >> 3)) : wg;
  const int nbn = N >> 8;
  const int bm = swz / nbn, bn = swz % nbn;
  const int m0 = bm << 8, n0 = bn << 8;

  const unsigned short* Ab = A + (size_t)m0 * K;
  const unsigned short* Bb = Bt + (size_t)n0 * K;

  f32x4 acc[8][4];
#pragma unroll
  for (int i = 0; i < 8; ++i)
#pragma unroll
    for (int j = 0; j < 4; ++j) acc[i][j] = (f32x4){0.f, 0.f, 0.f, 0.f};

  const int sw0 = ((kb) ^ (lr & 7)) << 4;
  const int sw1 = ((4 + kb) ^ (lr & 7)) << 4;

  STAGE_HALF(Asl[0], Ab, 0, 0); STAGE_HALF(Asl[0], Ab, 0, 1);
  STAGE_HALF(Bsl[0], Bb, 0, 0); STAGE_HALF(Bsl[0], Bb, 0, 1);
  __syncthreads();

  const int nt = K >> 6;
  bf16x8 af[4], bfr[4];

#pragma unroll 1
  for (int t = 0; t < nt; ++t) {
    const unsigned short* Acur = Asl[t & 1];
    const unsigned short* Bcur = Bsl[t & 1];
    unsigned short* Anxt = Asl[(t + 1) & 1];
    unsigned short* Bnxt = Bsl[(t + 1) & 1];
    const int k0n = (t + 1) << 6;
    const bool pf = (t + 1 < nt);

    // ---- phase 0: (mh=0, kk=0); stage A(t+1)
#pragma unroll
    for (int ni = 0; ni < 4; ++ni) bfr[ni] = LDF(Bcur, wc * 64 + ni * 16 + lr, sw0);
#pragma unroll
    for (int mi = 0; mi < 4; ++mi) af[mi] = LDF(Acur, wr * 128 + mi * 16 + lr, sw0);
    if (pf) { STAGE_HALF(Anxt, Ab, k0n, 0); STAGE_HALF(Anxt, Ab, k0n, 1); }
    PHASE_SYNC();
    __builtin_amdgcn_s_setprio(1);
#pragma unroll
    for (int mi = 0; mi < 4; ++mi)
#pragma unroll
      for (int ni = 0; ni < 4; ++ni)
        acc[mi][ni] = __builtin_amdgcn_mfma_f32_16x16x32_bf16(af[mi], bfr[ni], acc[mi][ni], 0, 0, 0);
    __builtin_amdgcn_s_setprio(0);
    __builtin_amdgcn_s_barrier();

    // ---- phase 1: (mh=1, kk=0); stage B(t+1)
#pragma unroll
    for (int mi = 0; mi < 4; ++mi) af[mi] = LDF(Acur, wr * 128 + (mi + 4) * 16 + lr, sw0);
    if (pf) { STAGE_HALF(Bnxt, Bb, k0n, 0); STAGE_HALF(Bnxt, Bb, k0n, 1); }
    PHASE_SYNC();
    __builtin_amdgcn_s_setprio(1);
#pragma unroll
    for (int mi = 0; mi < 4; ++mi)
#pragma unroll
      for (int ni = 0; ni < 4; ++ni)
        acc[mi + 4][ni] = __builtin_amdgcn_mfma_f32_16x16x32_bf16(af[mi], bfr[ni], acc[mi + 4][ni], 0, 0, 0);
    __builtin_amdgcn_s_setprio(0);
    __builtin_amdgcn_s_barrier();

    // ---- phase 2: (mh=0, kk=1)
#pragma unroll
    for (int ni = 0; ni < 4; ++ni) bfr[ni] = LDF(Bcur, wc * 64 + ni * 16 + lr, sw1);
#pragma unroll
    for (int mi = 0; mi < 4; ++mi) af[mi] = LDF(Acur, wr * 128 + mi * 16 + lr, sw1);
    PHASE_SYNC();
    __builtin_amdgcn_s_setprio(1);
#pragma unroll
    for (int mi = 0; mi < 4; ++mi)
#pragma unroll
      for (int ni = 0; ni < 4; ++ni)
        acc[mi][ni] = __builtin_amdgcn_mfma_f32_16x16x32_bf16(af[mi], bfr[ni], acc[mi][ni], 0, 0, 0);
    __builtin_amdgcn_s_setprio(0);
    __builtin_amdgcn_s_barrier();

    // ---- phase 3: (mh=1, kk=1)
#pragma unroll
    for (int mi = 0; mi < 4; ++mi) af[mi] = LDF(Acur, wr * 128 + (mi + 4) * 16 + lr, sw1);
    PHASE_SYNC();
    __builtin_amdgcn_s_setprio(1);
#pragma unroll
    for (int mi = 0; mi < 4; ++mi)
#pragma unroll
      for (int ni = 0; ni < 4; ++ni)
        acc[mi + 4][ni] = __builtin_amdgcn_mfma_f32_16x16x32_bf16(af[mi], bfr[ni], acc[mi + 4][ni], 0, 0, 0);
    __builtin_amdgcn_s_setprio(0);
    __builtin_amdgcn_s_barrier();

    if (pf) asm volatile("s_waitcnt vmcnt(0)" ::: "memory");
    __builtin_amdgcn_s_barrier();
  }

#pragma unroll
  for (int mi = 0; mi < 8; ++mi)
#pragma unroll
    for (int ni = 0; ni < 4; ++ni)
#pragma unroll
      for (int r = 0; r < 4; ++r) {
        int row = m0 + wr * 128 + mi * 16 + kb * 4 + r;
        int col = n0 + wc * 64 + ni * 16 + lr;
        store_out(&C[(size_t)row * N + col], acc[mi][ni][r]);
      }
}

// ---------------- flash attention (causal, GQA 32/8, D=128) ----------------
// r11-proven body (165 us): 32 q-rows/wave, QBLK=128, KVBLK=64, K dbuf+prefetch,
// one syncthreads/step, exp2-domain softmax, cvt_pk P-pack, P stride 72.
// PAIRED grid (8,64): qt = {15-pr, pr} -> uniform 34 steps; all 512 blocks
// co-resident (2/CU) -> zero load imbalance (r15 lesson: unpairing regresses).
__global__ __launch_bounds__(256, 2) void attn_fwd(const unsigned short* __restrict__ Q,
                                                   const unsigned short* __restrict__ KV,
                                                   const unsigned short* __restrict__ Vt,
                                                   const float* __restrict__ cosT,
                                                   const float* __restrict__ sinT,
                                                   unsigned short* __restrict__ O) {
  __shared__ unsigned short Ks[2][64 * 128];   // 32 KB (double buffer)
  __shared__ unsigned short Ps[4][2][16 * 72]; // 18.4 KB
  const int tid = threadIdx.x, lane = tid & 63, wave = tid >> 6;
  const int lr = lane & 15, kb = lane >> 4;
  const int pr = blockIdx.x;           // 0..7 (pair index)
  const int bh = blockIdx.y;           // 0..63
  const int b = bh >> 5, h = bh & 31, kvh = h >> 2;
  const unsigned short* Qp = Q + (size_t)b * S_LEN * HID_DIM + (size_t)h * HD;
  const unsigned short* Kp = KV + (size_t)b * S_LEN * KV2 + (size_t)kvh * HD;
  const unsigned short* Vtp = Vt + (size_t)(b * 8 + kvh) * HD * S_LEN;  // [128][2048]
  unsigned short* Op = O + (size_t)b * S_LEN * HID_DIM + (size_t)h * HD;

#pragma unroll 1
  for (int pass = 0; pass < 2; ++pass) {
    const int qt = pass ? pr : 15 - pr;
    const int q0 = qt * 128;
    int qrowQ[2];
    qrowQ[0] = q0 + wave * 32 + lr;
    qrowQ[1] = q0 + wave * 32 + 16 + lr;

    // ---- load raw Q + fused RoPE + scale (1/sqrt(128) * log2e folded) ----
    bf16x8 qf[2][4];
#pragma unroll
    for (int qs = 0; qs < 2; ++qs) {
      const int qrow = qrowQ[qs];
      bf16x8 raw[4];
#pragma unroll
      for (int dc = 0; dc < 4; ++dc)
        raw[dc] = *reinterpret_cast<const bf16x8*>(Qp + (size_t)qrow * HID_DIM + dc * 32 + kb * 8);
      const float* ct = cosT + (qrow << 6) + kb * 8;
      const float* st = sinT + (qrow << 6) + kb * 8;
      f32x4 cv0 = *(const f32x4*)(ct),      cv1 = *(const f32x4*)(ct + 4);
      f32x4 cv2 = *(const f32x4*)(ct + 32), cv3 = *(const f32x4*)(ct + 36);
      f32x4 sv0 = *(const f32x4*)(st),      sv1 = *(const f32x4*)(st + 4);
      f32x4 sv2 = *(const f32x4*)(st + 32), sv3 = *(const f32x4*)(st + 36);
      const float sc = 0.08838834764831843f * 1.4426950408889634f;  // 1/sqrt(128) * log2(e)
#pragma unroll
      for (int j = 0; j < 8; ++j) {
        const int jj = j & 3;
        float c0 = (j < 4) ? cv0[jj] : cv1[jj];
        float s0 = (j < 4) ? sv0[jj] : sv1[jj];
        float c1 = (j < 4) ? cv2[jj] : cv3[jj];
        float s1 = (j < 4) ? sv2[jj] : sv3[jj];
        float a1 = b2f((unsigned short)raw[0][j]), a2 = b2f((unsigned short)raw[2][j]);
        qf[qs][0][j] = (short)f2b((a1 * c0 - a2 * s0) * sc);
        qf[qs][2][j] = (short)f2b((a2 * c0 + a1 * s0) * sc);
        float b1 = b2f((unsigned short)raw[1][j]), b2x = b2f((unsigned short)raw[3][j]);
        qf[qs][1][j] = (short)f2b((b1 * c1 - b2x * s1) * sc);
        qf[qs][3][j] = (short)f2b((b2x * c1 + b1 * s1) * sc);
      }
    }

    f32x4 of[2][8];
#pragma unroll
    for (int qs = 0; qs < 2; ++qs)
#pragma unroll
      for (int i = 0; i < 8; ++i) of[qs][i] = (f32x4){0.f, 0.f, 0.f, 0.f};
    float mrow[2] = {-3.0e38f, -3.0e38f};
    float lrow[2] = {0.f, 0.f};

    const int nsteps = 2 * qt + 2;       // 64-key steps covering q0+128 keys

    // ---- prologue: stage tile 0 into Ks[0]
#pragma unroll
    for (int i = 0; i < 4; ++i) {
      int c = i * 256 + tid;
      int key = c >> 4;
      int ch = (c & 15) ^ (key & 7);
      gload_lds16(Kp + (size_t)key * KV2 + ch * 8, &Ks[0][0] + c * 8);
    }
    __syncthreads();   // tile 0 visible

#pragma unroll 1
    for (int t = 0; t < nsteps; ++t) {
      const int kv0 = t << 6;
      const unsigned short* Kcur = &Ks[t & 1][0];

      // --- V group-0 loads FIRST (PV0 waits only these; prefetch stays in flight)
      bf16x8 vf[8];
#pragma unroll
      for (int dc2 = 0; dc2 < 8; ++dc2)
        vf[dc2] = *reinterpret_cast<const bf16x8*>(
            Vtp + (size_t)(dc2 * 16 + lr) * S_LEN + kv0 + kb * 8);

      // --- prefetch next K tile (drained only at step-end barrier)
      if (t + 1 < nsteps) {
        unsigned short* Knxt = &Ks[(t + 1) & 1][0];
#pragma unroll
        for (int i = 0; i < 4; ++i) {
          int c = i * 256 + tid;
          int key = c >> 4;
          int ch = (c & 15) ^ (key & 7);
          gload_lds16(Kp + (size_t)(kv0 + 64 + key) * KV2 + ch * 8, Knxt + c * 8);
        }
      }

      // --- S^T = K Q^T : kf shared across q-sets
      f32x4 sf[2][4];
#pragma unroll
      for (int qs = 0; qs < 2; ++qs)
#pragma unroll
        for (int ki = 0; ki < 4; ++ki) sf[qs][ki] = (f32x4){0.f, 0.f, 0.f, 0.f};
#pragma unroll
      for (int ki = 0; ki < 4; ++ki)
#pragma unroll
        for (int dc = 0; dc < 4; ++dc) {
          bf16x8 kf = *reinterpret_cast<const bf16x8*>(
              Kcur + (ki * 16 + lr) * 128 + (((dc * 4 + kb) ^ (lr & 7)) << 3));
          sf[0][ki] = __builtin_amdgcn_mfma_f32_16x16x32_bf16(kf, qf[0][dc], sf[0][ki], 0, 0, 0);
          sf[1][ki] = __builtin_amdgcn_mfma_f32_16x16x32_bf16(kf, qf[1][dc], sf[1][ki], 0, 0, 0);
        }

      // --- causal mask per q-set (wave-uniform skip)
#pragma unroll
      for (int qs = 0; qs < 2; ++qs) {
        if (kv0 + 63 > q0 + wave * 32 + qs * 16) {
          const int thr = qrowQ[qs] - kv0;
#pragma unroll
          for (int ki = 0; ki < 4; ++ki)
#pragma unroll
            for (int r = 0; r < 4; ++r)
              if (ki * 16 + kb * 4 + r > thr) sf[qs][ki][r] = -3.0e38f;
        }
      }

      // --- two independent softmax chains (log2 domain), defer-max THR=11.5 bits
#pragma unroll
      for (int qs = 0; qs < 2; ++qs) {
        float m8 = -3.0e38f;
#pragma unroll
        for (int ki = 0; ki < 4; ++ki)
#pragma unroll
          for (int r = 0; r < 4; ++r) m8 = fmaxf(m8, sf[qs][ki][r]);
        m8 = fmaxf(m8, __shfl_xor(m8, 16));
        m8 = fmaxf(m8, __shfl_xor(m8, 32));
        if (__any(m8 > mrow[qs] + 11.5f)) {
          float mn = fmaxf(mrow[qs], m8);
          float corr = exp2fast(mrow[qs] - mn);
          lrow[qs] *= corr;
#pragma unroll
          for (int r = 0; r < 4; ++r) {
            float cr = __shfl(corr, kb * 4 + r);
#pragma unroll
            for (int dc2 = 0; dc2 < 8; ++dc2) of[qs][dc2][r] *= cr;
          }
          mrow[qs] = mn;
        }
        float rs = 0.f;
#pragma unroll
        for (int ki = 0; ki < 4; ++ki) {
          float p0 = exp2fast(sf[qs][ki][0] - mrow[qs]);   // bounded by 2^11.5
          float p1 = exp2fast(sf[qs][ki][1] - mrow[qs]);
          float p2 = exp2fast(sf[qs][ki][2] - mrow[qs]);
          float p3 = exp2fast(sf[qs][ki][3] - mrow[qs]);
          rs += (p0 + p1) + (p2 + p3);
          uint2 w;
          w.x = cvtpk(p0, p1);
          w.y = cvtpk(p2, p3);
          *reinterpret_cast<uint2*>(&Ps[wave][qs][lr * 72 + ki * 16 + kb * 4]) = w;
        }
        rs += __shfl_xor(rs, 16);
        rs += __shfl_xor(rs, 32);
        lrow[qs] += rs;
      }
      asm volatile("s_waitcnt lgkmcnt(0)" ::: "memory");
      __builtin_amdgcn_sched_barrier(0);

      // --- PV group 0 (keys kv0..+31), both q-sets share vf
      {
        bf16x8 pf0 = *reinterpret_cast<const bf16x8*>(&Ps[wave][0][lr * 72 + kb * 8]);
        bf16x8 pf1 = *reinterpret_cast<const bf16x8*>(&Ps[wave][1][lr * 72 + kb * 8]);
#pragma unroll
        for (int dc2 = 0; dc2 < 8; ++dc2) {
          of[0][dc2] = __builtin_amdgcn_mfma_f32_16x16x32_bf16(pf0, vf[dc2], of[0][dc2], 0, 0, 0);
          of[1][dc2] = __builtin_amdgcn_mfma_f32_16x16x32_bf16(pf1, vf[dc2], of[1][dc2], 0, 0, 0);
        }
      }
      // --- V group 1 + PV group 1
#pragma unroll
      for (int dc2 = 0; dc2 < 8; ++dc2)
        vf[dc2] = *reinterpret_cast<const bf16x8*>(
            Vtp + (size_t)(dc2 * 16 + lr) * S_LEN + kv0 + 32 + kb * 8);
      {
        bf16x8 pf0 = *reinterpret_cast<const bf16x8*>(&Ps[wave][0][lr * 72 + 32 + kb * 8]);
        bf16x8 pf1 = *reinterpret_cast<const bf16x8*>(&Ps[wave][1][lr * 72 + 32 + kb * 8]);
#pragma unroll
        for (int dc2 = 0; dc2 < 8; ++dc2) {
          of[0][dc2] = __builtin_amdgcn_mfma_f32_16x16x32_bf16(pf0, vf[dc2], of[0][dc2], 0, 0, 0);
          of[1][dc2] = __builtin_amdgcn_mfma_f32_16x16x32_bf16(pf1, vf[dc2], of[1][dc2], 0, 0, 0);
        }
      }

      __syncthreads();  // one drain/step: prefetch resident; all Kcur reads done
    }

    // --- normalize + write (of[qs] row q = kb*4+r; lrow lives at lane lr = q)
#pragma unroll
    for (int qs = 0; qs < 2; ++qs) {
      float linv[4];
#pragma unroll
      for (int r = 0; r < 4; ++r) linv[r] = 1.0f / __shfl(lrow[qs], kb * 4 + r);
#pragma unroll
      for (int dc2 = 0; dc2 < 8; ++dc2)
#pragma unroll
        for (int r = 0; r < 4; ++r) {
          int qg = q0 + wave * 32 + qs * 16 + kb * 4 + r;
          Op[(size_t)qg * HID_DIM + dc2 * 16 + lr] = f2b(of[qs][dc2][r] * linv[r]);
        }
    }
  }
}

// ---------------- launch ----------------
extern "C" void kernel_launch(void* const* d_in, const int* in_sizes, int n_in,
                              void* d_out, int out_size, void* d_ws, size_t ws_size,
                              hipStream_t stream) {
  const float* x  = (const float*)d_in[0];
  const float* Wq = (const float*)d_in[2];
  const float* Wk = (const float*)d_in[3];
  const float* Wv = (const float*)d_in[4];
  const float* Wo = (const float*)d_in[5];
  float* out = (float*)d_out;

  char* ws = (char*)d_ws;
  unsigned short* xb  = (unsigned short*)(ws + 0);          // 33.5MB (later reused as AO)
  unsigned short* wtb = (unsigned short*)(ws + 33554432);   // Wq^T; later Wo^T
  unsigned short* wkt = (unsigned short*)(ws + 67108864);   // Wk^T | Wv^T contiguous; later Vt
  unsigned short* wvt = (unsigned short*)(ws + 75497472);
  unsigned short* Qb  = (unsigned short*)(ws + 83886080);
  unsigned short* KVb = (unsigned short*)(ws + 117440512);  // [4096][2048] fused K|V
  float* cosT = (float*)(ws + 134217728);
  float* sinT = (float*)(ws + 134742016);
  unsigned short* AO  = xb;   // alias: x dead after KV projection
  unsigned short* Vtb = wkt;  // alias: Wk^T/Wv^T dead after KV projection
  unsigned short* woT = wtb;  // alias: Wq^T dead after Q projection

  prep_k<<<41472, 256, 0, stream>>>(x, xb, Wq, wtb, Wk, wkt, Wv, wvt, cosT, sinT);

  gemm256<unsigned short><<<256, 512, 0, stream>>>(xb, wtb, Qb, BS_ROWS, HID_DIM, HID_DIM);  // raw Q
  gemm_bt<unsigned short><<<512, 256, 0, stream>>>(xb, wkt, KVb, BS_ROWS, KV2, HID_DIM);     // fused K|V

  // K-RoPE + V transpose + Wo transpose (wkt/wtb regions now dead -> Vt/woT)
  postkv_k<<<22528, 256, 0, stream>>>(KVb, Vtb, Wo, woT, cosT, sinT);

  attn_fwd<<<dim3(8, 64), 256, 0, stream>>>(Qb, KVb, Vtb, cosT, sinT, AO);

  gemm256<float><<<256, 512, 0, stream>>>(AO, woT, out, BS_ROWS, HID_DIM, HID_DIM);
}

// Round 17
// 543.313 us; speedup vs baseline: 1.1978x; 1.0000x over previous
//
#include <hip/hip_runtime.h>

#define S_LEN   2048
#define HID_DIM 4096
#define NHEADS  32
#define NKVH    8
#define HD      128
#define KV_DIM  1024
#define KV2     2048   // fused K|V row stride
#define BS_ROWS 4096   // B * S

typedef __attribute__((ext_vector_type(4))) float f32x4;
typedef __attribute__((ext_vector_type(8))) short bf16x8;

// ---------------- helpers ----------------
__device__ __forceinline__ unsigned short f2b(float f) {
  union { float f; unsigned int u; } cv; cv.f = f;
  unsigned int r = (cv.u + 0x7FFFu + ((cv.u >> 16) & 1u)) >> 16;  // RNE
  return (unsigned short)r;
}
__device__ __forceinline__ float b2f(unsigned short u) {
  union { unsigned int u; float f; } cv; cv.u = ((unsigned int)u) << 16; return cv.f;
}
__device__ __forceinline__ void gload_lds16(const void* g, void* l) {
  __builtin_amdgcn_global_load_lds(
      (const __attribute__((address_space(1))) unsigned int*)g,
      (__attribute__((address_space(3))) unsigned int*)l, 16, 0, 0);
}
__device__ __forceinline__ float exp2fast(float x) {
#if __has_builtin(__builtin_amdgcn_exp2f)
  return __builtin_amdgcn_exp2f(x);
#else
  return exp2f(x);
#endif
}
__device__ __forceinline__ unsigned cvtpk(float a, float b) {
  unsigned r;
  asm("v_cvt_pk_bf16_f32 %0, %1, %2" : "=v"(r) : "v"(a), "v"(b));
  return r;
}
__device__ __forceinline__ void store_out(float* p, float v) { *p = v; }
__device__ __forceinline__ void store_out(unsigned short* p, float v) { *p = f2b(v); }

// ---------------- fused prep: cvt(x) + transpose(Wq,Wk,Wv) + rope tables ----------
// block ranges: [0,16384) cvt | [16384,32768) tWq | [32768,36864) tWk |
//               [36864,40960) tWv | [40960,41472) rope tables
__global__ __launch_bounds__(256) void prep_k(const float* __restrict__ x,
                                              unsigned short* __restrict__ xb,
                                              const float* __restrict__ Wq,
                                              unsigned short* __restrict__ wtq,
                                              const float* __restrict__ Wk,
                                              unsigned short* __restrict__ wtk,
                                              const float* __restrict__ Wv,
                                              unsigned short* __restrict__ wtv,
                                              float* __restrict__ cosT,
                                              float* __restrict__ sinT) {
  __shared__ float t[32][33];
  int bid = blockIdx.x;
  const int tid = threadIdx.x;
  if (bid < 16384) {                       // ---- cvt x -> bf16 (exact grid)
    int i = bid * 256 + tid;
    f32x4 v = reinterpret_cast<const f32x4*>(x)[i];
    ushort4 o;
    o.x = f2b(v[0]); o.y = f2b(v[1]); o.z = f2b(v[2]); o.w = f2b(v[3]);
    reinterpret_cast<ushort4*>(xb)[i] = o;
    return;
  }
  bid -= 16384;
  const float* W; unsigned short* Wt; int Nd, bx, by;
  if (bid < 16384) { W = Wq; Wt = wtq; Nd = HID_DIM; bx = bid & 127; by = bid >> 7; }
  else {
    bid -= 16384;
    if (bid < 4096) { W = Wk; Wt = wtk; Nd = KV_DIM; bx = bid & 31; by = bid >> 5; }
    else {
      bid -= 4096;
      if (bid < 4096) { W = Wv; Wt = wtv; Nd = KV_DIM; bx = bid & 31; by = bid >> 5; }
      else {                               // ---- rope tables (exact grid)
        bid -= 4096;
        int idx = bid * 256 + tid;         // < S_LEN*64
        int s = idx >> 6, i = idx & 63;
        float inv = 1.0f / powf(10000.0f, (float)(2 * i) * (1.0f / 128.0f));
        float ang = (float)s * inv;
        cosT[idx] = cosf(ang);
        sinT[idx] = sinf(ang);
        return;
      }
    }
  }
  // ---- transpose+convert tile (proven body; tx=tid&31, ty=tid>>5)
  const int tx = tid & 31, ty = tid >> 5;
  const int n0 = bx * 32, k0 = by * 32;
#pragma unroll
  for (int i = 0; i < 4; ++i)
    t[ty + 8 * i][tx] = W[(size_t)(k0 + ty + 8 * i) * Nd + n0 + tx];
  __syncthreads();
#pragma unroll
  for (int i = 0; i < 4; ++i)
    Wt[(size_t)(n0 + ty + 8 * i) * HID_DIM + k0 + tx] = f2b(t[tx][ty + 8 * i]);
}

// ---------------- fused post-KV: K-RoPE + V transpose + Wo transpose ----------------
// block ranges: [0,2048) ropeK | [2048,6144) transpose_v | [6144,22528) transpose_Wo
__global__ __launch_bounds__(256) void postkv_k(unsigned short* __restrict__ KVb,
                                                unsigned short* __restrict__ Vt,
                                                const float* __restrict__ Wo,
                                                unsigned short* __restrict__ woT,
                                                const float* __restrict__ cosT,
                                                const float* __restrict__ sinT) {
  __shared__ float tf[32][33];
  __shared__ unsigned short tsh[32][33];
  int bid = blockIdx.x;
  const int tid = threadIdx.x;
  if (bid < 2048) {                        // ---- RoPE on K half (4 pairs/thread)
    int idx = bid * 256 + tid;             // < BS_ROWS*NKVH*16
    int i4 = idx & 15;
    int t = idx >> 4;
    int h = t & (NKVH - 1);
    int row = t >> 3;                      // t / NKVH
    int s = row & (S_LEN - 1);
    f32x4 c4 = *reinterpret_cast<const f32x4*>(&cosT[(s << 6) + i4 * 4]);
    f32x4 s4 = *reinterpret_cast<const f32x4*>(&sinT[(s << 6) + i4 * 4]);
    size_t base = (size_t)row * KV2 + (size_t)h * HD + i4 * 4;
    ushort4 xa = *reinterpret_cast<const ushort4*>(&KVb[base]);
    ushort4 xb2 = *reinterpret_cast<const ushort4*>(&KVb[base + 64]);
    unsigned short* pa = (unsigned short*)&xa;
    unsigned short* pb = (unsigned short*)&xb2;
    ushort4 oa, ob;
    unsigned short* qa = (unsigned short*)&oa;
    unsigned short* qb = (unsigned short*)&ob;
#pragma unroll
    for (int j = 0; j < 4; ++j) {
      float x1 = b2f(pa[j]), x2 = b2f(pb[j]);
      qa[j] = f2b(x1 * c4[j] - x2 * s4[j]);
      qb[j] = f2b(x2 * c4[j] + x1 * s4[j]);
    }
    *reinterpret_cast<ushort4*>(&KVb[base])      = oa;
    *reinterpret_cast<ushort4*>(&KVb[base + 64]) = ob;
    return;
  }
  bid -= 2048;
  const int tx = tid & 31, ty = tid >> 5;
  if (bid < 4096) {                        // ---- V transpose (proven body, strided src)
    int c0 = (bid & 31) * 32;              // col base 0..1023 (within V half)
    int r0 = (bid >> 5) * 32;              // row base 0..4095
#pragma unroll
    for (int i = 0; i < 4; ++i)
      tsh[ty + 8 * i][tx] = KVb[(size_t)(r0 + ty + 8 * i) * KV2 + KV_DIM + c0 + tx];
    __syncthreads();
    int ob2 = (r0 >> 11) * 1024;           // b * (8 kvh * 128 d)
    int oc = r0 & 2047;                    // s base
#pragma unroll
    for (int i = 0; i < 4; ++i)
      Vt[(size_t)(ob2 + c0 + ty + 8 * i) * S_LEN + oc + tx] = tsh[tx][ty + 8 * i];
    return;
  }
  bid -= 4096;                             // ---- Wo transpose+convert (proven body)
  {
    int n0 = (bid & 127) * 32, k0 = (bid >> 7) * 32;
#pragma unroll
    for (int i = 0; i < 4; ++i)
      tf[ty + 8 * i][tx] = Wo[(size_t)(k0 + ty + 8 * i) * HID_DIM + n0 + tx];
    __syncthreads();
#pragma unroll
    for (int i = 0; i < 4; ++i)
      woT[(size_t)(n0 + ty + 8 * i) * HID_DIM + k0 + tx] = f2b(tf[tx][ty + 8 * i]);
  }
}

// ---------------- 128-tile bf16 MFMA GEMM (m97 structure) — KV proj ----------
template <typename OutT>
__global__ __launch_bounds__(256) void gemm_bt(const unsigned short* __restrict__ A,
                                               const unsigned short* __restrict__ Bt,
                                               OutT* __restrict__ C, int M, int N, int K) {
  __shared__ unsigned short As[128 * 32];
  __shared__ unsigned short Bs[128 * 32];
  const int tid = threadIdx.x;
  const int lane = tid & 63;
  const int wave = tid >> 6;
  int nwg = gridDim.x, wg = blockIdx.x;
  int swz = (nwg % 8 == 0) ? ((wg & 7) * (nwg >> 3) + (wg >> 3)) : wg;
  const int nbn = N >> 7;
  const int bm = swz / nbn, bn = swz % nbn;
  const int m0 = bm << 7, n0 = bn << 7;
  const int wr = wave >> 1, wc = wave & 1;
  const int lr = lane & 15, kb = lane >> 4;

  f32x4 acc[4][4];
#pragma unroll
  for (int i = 0; i < 4; ++i)
#pragma unroll
    for (int j = 0; j < 4; ++j) acc[i][j] = (f32x4){0.f, 0.f, 0.f, 0.f};

  const unsigned short* Ab = A + (size_t)m0 * K;
  const unsigned short* Bb = Bt + (size_t)n0 * K;

  for (int k0 = 0; k0 < K; k0 += 32) {
    __syncthreads();
#pragma unroll
    for (int i = 0; i < 2; ++i) {
      int idx = i * 256 + tid;
      int row = idx >> 2;
      int off = (idx & 3) << 3;
      gload_lds16(Ab + (size_t)row * K + k0 + off, As + row * 32 + off);
      gload_lds16(Bb + (size_t)row * K + k0 + off, Bs + row * 32 + off);
    }
    __syncthreads();

    bf16x8 af[4], bfr[4];
#pragma unroll
    for (int mi = 0; mi < 4; ++mi)
      af[mi] = *reinterpret_cast<const bf16x8*>(As + (wr * 64 + mi * 16 + lr) * 32 + kb * 8);
#pragma unroll
    for (int ni = 0; ni < 4; ++ni)
      bfr[ni] = *reinterpret_cast<const bf16x8*>(Bs + (wc * 64 + ni * 16 + lr) * 32 + kb * 8);
#pragma unroll
    for (int mi = 0; mi < 4; ++mi)
#pragma unroll
      for (int ni = 0; ni < 4; ++ni)
        acc[mi][ni] = __builtin_amdgcn_mfma_f32_16x16x32_bf16(af[mi], bfr[ni], acc[mi][ni], 0, 0, 0);
  }

#pragma unroll
  for (int mi = 0; mi < 4; ++mi)
#pragma unroll
    for (int ni = 0; ni < 4; ++ni)
#pragma unroll
      for (int r = 0; r < 4; ++r) {
        int row = m0 + wr * 64 + mi * 16 + kb * 4 + r;
        int col = n0 + wc * 64 + ni * 16 + lr;
        store_out(&C[(size_t)row * N + col], acc[mi][ni][r]);
      }
}

// ---------------- 256-tile 8-wave 4-phase GEMM (T2+T3+T4+T5) — Q/O proj ----------
#define STAGE_HALF(dstBase, Sp, k0, h)                                           \
  {                                                                              \
    _Pragma("unroll")                                                            \
    for (int i_ = 0; i_ < 2; ++i_) {                                             \
      int c_ = i_ * 512 + tid;                                                   \
      int rl_ = c_ >> 3, ch_ = c_ & 7;                                           \
      int row_ = (h) * 128 + rl_;                                                \
      gload_lds16((Sp) + (size_t)row_ * K + (k0) + ((ch_ ^ (row_ & 7)) << 3),    \
                  (char*)(dstBase) + row_ * 128 + ch_ * 16);                     \
    }                                                                            \
  }
#define LDF(buf, R, sw) \
  (*reinterpret_cast<const bf16x8*>((const char*)(buf) + (R) * 128 + (sw)))
#define PHASE_SYNC()                                        \
  __builtin_amdgcn_s_barrier();                             \
  asm volatile("s_waitcnt lgkmcnt(0)" ::: "memory");        \
  __builtin_amdgcn_sched_barrier(0);

template <typename OutT>
__global__ __launch_bounds__(512, 1) void gemm256(const unsigned short* __restrict__ A,
                                                  const unsigned short* __restrict__ Bt,
                                                  OutT* __restrict__ C, int M, int N, int K) {
  __shared__ unsigned short Asl[2][256 * 64];
  __shared__ unsigned short Bsl[2][256 * 64];
  const int tid = threadIdx.x;
  const int lane = tid & 63;
  const int wave = tid >> 6;       // 0..7
  const int wr = wave >> 2;        // 0..1  (M)
  const int wc = wave & 3;         // 0..3  (N)
  const int lr = lane & 15, kb = lane >> 4;

  int nwg = gridDim.x, wg = blockIdx.x;
  int swz = (nwg % 8 == 0) ? ((wg & 7) * (nwg >> 3) + (wg >> 3)) : wg;
  const int nbn = N >> 8;
  const int bm = swz / nbn, bn = swz % nbn;
  const int m0 = bm << 8, n0 = bn << 8;

  const unsigned short* Ab = A + (size_t)m0 * K;
  const unsigned short* Bb = Bt + (size_t)n0 * K;

  f32x4 acc[8][4];
#pragma unroll
  for (int i = 0; i < 8; ++i)
#pragma unroll
    for (int j = 0; j < 4; ++j) acc[i][j] = (f32x4){0.f, 0.f, 0.f, 0.f};

  const int sw0 = ((kb) ^ (lr & 7)) << 4;
  const int sw1 = ((4 + kb) ^ (lr & 7)) << 4;

  STAGE_HALF(Asl[0], Ab, 0, 0); STAGE_HALF(Asl[0], Ab, 0, 1);
  STAGE_HALF(Bsl[0], Bb, 0, 0); STAGE_HALF(Bsl[0], Bb, 0, 1);
  __syncthreads();

  const int nt = K >> 6;
  bf16x8 af[4], bfr[4];

#pragma unroll 1
  for (int t = 0; t < nt; ++t) {
    const unsigned short* Acur = Asl[t & 1];
    const unsigned short* Bcur = Bsl[t & 1];
    unsigned short* Anxt = Asl[(t + 1) & 1];
    unsigned short* Bnxt = Bsl[(t + 1) & 1];
    const int k0n = (t + 1) << 6;
    const bool pf = (t + 1 < nt);

    // ---- phase 0: (mh=0, kk=0); stage A(t+1)
#pragma unroll
    for (int ni = 0; ni < 4; ++ni) bfr[ni] = LDF(Bcur, wc * 64 + ni * 16 + lr, sw0);
#pragma unroll
    for (int mi = 0; mi < 4; ++mi) af[mi] = LDF(Acur, wr * 128 + mi * 16 + lr, sw0);
    if (pf) { STAGE_HALF(Anxt, Ab, k0n, 0); STAGE_HALF(Anxt, Ab, k0n, 1); }
    PHASE_SYNC();
    __builtin_amdgcn_s_setprio(1);
#pragma unroll
    for (int mi = 0; mi < 4; ++mi)
#pragma unroll
      for (int ni = 0; ni < 4; ++ni)
        acc[mi][ni] = __builtin_amdgcn_mfma_f32_16x16x32_bf16(af[mi], bfr[ni], acc[mi][ni], 0, 0, 0);
    __builtin_amdgcn_s_setprio(0);
    __builtin_amdgcn_s_barrier();

    // ---- phase 1: (mh=1, kk=0); stage B(t+1)
#pragma unroll
    for (int mi = 0; mi < 4; ++mi) af[mi] = LDF(Acur, wr * 128 + (mi + 4) * 16 + lr, sw0);
    if (pf) { STAGE_HALF(Bnxt, Bb, k0n, 0); STAGE_HALF(Bnxt, Bb, k0n, 1); }
    PHASE_SYNC();
    __builtin_amdgcn_s_setprio(1);
#pragma unroll
    for (int mi = 0; mi < 4; ++mi)
#pragma unroll
      for (int ni = 0; ni < 4; ++ni)
        acc[mi + 4][ni] = __builtin_amdgcn_mfma_f32_16x16x32_bf16(af[mi], bfr[ni], acc[mi + 4][ni], 0, 0, 0);
    __builtin_amdgcn_s_setprio(0);
    __builtin_amdgcn_s_barrier();

    // ---- phase 2: (mh=0, kk=1)
#pragma unroll
    for (int ni = 0; ni < 4; ++ni) bfr[ni] = LDF(Bcur, wc * 64 + ni * 16 + lr, sw1);
#pragma unroll
    for (int mi = 0; mi < 4; ++mi) af[mi] = LDF(Acur, wr * 128 + mi * 16 + lr, sw1);
    PHASE_SYNC();
    __builtin_amdgcn_s_setprio(1);
#pragma unroll
    for (int mi = 0; mi < 4; ++mi)
#pragma unroll
      for (int ni = 0; ni < 4; ++ni)
        acc[mi][ni] = __builtin_amdgcn_mfma_f32_16x16x32_bf16(af[mi], bfr[ni], acc[mi][ni], 0, 0, 0);
    __builtin_amdgcn_s_setprio(0);
    __builtin_amdgcn_s_barrier();

    // ---- phase 3: (mh=1, kk=1)
#pragma unroll
    for (int mi = 0; mi < 4; ++mi) af[mi] = LDF(Acur, wr * 128 + (mi + 4) * 16 + lr, sw1);
    PHASE_SYNC();
    __builtin_amdgcn_s_setprio(1);
#pragma unroll
    for (int mi = 0; mi < 4; ++mi)
#pragma unroll
      for (int ni = 0; ni < 4; ++ni)
        acc[mi + 4][ni] = __builtin_amdgcn_mfma_f32_16x16x32_bf16(af[mi], bfr[ni], acc[mi + 4][ni], 0, 0, 0);
    __builtin_amdgcn_s_setprio(0);
    __builtin_amdgcn_s_barrier();

    if (pf) asm volatile("s_waitcnt vmcnt(0)" ::: "memory");
    __builtin_amdgcn_s_barrier();
  }

#pragma unroll
  for (int mi = 0; mi < 8; ++mi)
#pragma unroll
    for (int ni = 0; ni < 4; ++ni)
#pragma unroll
      for (int r = 0; r < 4; ++r) {
        int row = m0 + wr * 128 + mi * 16 + kb * 4 + r;
        int col = n0 + wc * 64 + ni * 16 + lr;
        store_out(&C[(size_t)row * N + col], acc[mi][ni][r]);
      }
}

// ---------------- flash attention (causal, GQA 32/8, D=128) ----------------
// r14-proven body + XCD-pinned block decode: flat = bx + 8*by; kvh = flat&7 so
// all 64 blocks sharing a kvh land on ONE XCD (8 XCDs x 32 CUs x 2 blocks).
// K+Vt working set per XCD = 2 MB < 4 MB L2 -> K/V fetched once chip-wide.
// Bijection: (kvh, pr, hi, b) <- (flat&7, j&7, (j>>3)&3, j>>5), j = flat>>3.
__global__ __launch_bounds__(256, 2) void attn_fwd(const unsigned short* __restrict__ Q,
                                                   const unsigned short* __restrict__ KV,
                                                   const unsigned short* __restrict__ Vt,
                                                   const float* __restrict__ cosT,
                                                   const float* __restrict__ sinT,
                                                   unsigned short* __restrict__ O) {
  __shared__ unsigned short Ks[2][64 * 128];   // 32 KB (double buffer)
  __shared__ unsigned short Ps[4][2][16 * 72]; // 18.4 KB
  const int tid = threadIdx.x, lane = tid & 63, wave = tid >> 6;
  const int lr = lane & 15, kb = lane >> 4;
  const int flat = blockIdx.x + 8 * blockIdx.y;   // 0..511, XCD = flat & 7
  const int kvh = flat & 7;
  const int j = flat >> 3;             // 0..63
  const int pr = j & 7;                // pair index 0..7
  const int hi = (j >> 3) & 3;         // head within kvh group
  const int b = j >> 5;                // batch
  const int h = kvh * 4 + hi;
  const unsigned short* Qp = Q + (size_t)b * S_LEN * HID_DIM + (size_t)h * HD;
  const unsigned short* Kp = KV + (size_t)b * S_LEN * KV2 + (size_t)kvh * HD;
  const unsigned short* Vtp = Vt + (size_t)(b * 8 + kvh) * HD * S_LEN;  // [128][2048]
  unsigned short* Op = O + (size_t)b * S_LEN * HID_DIM + (size_t)h * HD;

#pragma unroll 1
  for (int pass = 0; pass < 2; ++pass) {
    const int qt = pass ? pr : 15 - pr;
    const int q0 = qt * 128;
    int qrowQ[2];
    qrowQ[0] = q0 + wave * 32 + lr;
    qrowQ[1] = q0 + wave * 32 + 16 + lr;

    // ---- load raw Q + fused RoPE + scale (1/sqrt(128) * log2e folded) ----
    bf16x8 qf[2][4];
#pragma unroll
    for (int qs = 0; qs < 2; ++qs) {
      const int qrow = qrowQ[qs];
      bf16x8 raw[4];
#pragma unroll
      for (int dc = 0; dc < 4; ++dc)
        raw[dc] = *reinterpret_cast<const bf16x8*>(Qp + (size_t)qrow * HID_DIM + dc * 32 + kb * 8);
      const float* ct = cosT + (qrow << 6) + kb * 8;
      const float* st = sinT + (qrow << 6) + kb * 8;
      f32x4 cv0 = *(const f32x4*)(ct),      cv1 = *(const f32x4*)(ct + 4);
      f32x4 cv2 = *(const f32x4*)(ct + 32), cv3 = *(const f32x4*)(ct + 36);
      f32x4 sv0 = *(const f32x4*)(st),      sv1 = *(const f32x4*)(st + 4);
      f32x4 sv2 = *(const f32x4*)(st + 32), sv3 = *(const f32x4*)(st + 36);
      const float sc = 0.08838834764831843f * 1.4426950408889634f;  // 1/sqrt(128) * log2(e)
#pragma unroll
      for (int jx = 0; jx < 8; ++jx) {
        const int jj = jx & 3;
        float c0 = (jx < 4) ? cv0[jj] : cv1[jj];
        float s0 = (jx < 4) ? sv0[jj] : sv1[jj];
        float c1 = (jx < 4) ? cv2[jj] : cv3[jj];
        float s1 = (jx < 4) ? sv2[jj] : sv3[jj];
        float a1 = b2f((unsigned short)raw[0][jx]), a2 = b2f((unsigned short)raw[2][jx]);
        qf[qs][0][jx] = (short)f2b((a1 * c0 - a2 * s0) * sc);
        qf[qs][2][jx] = (short)f2b((a2 * c0 + a1 * s0) * sc);
        float b1 = b2f((unsigned short)raw[1][jx]), b2x = b2f((unsigned short)raw[3][jx]);
        qf[qs][1][jx] = (short)f2b((b1 * c1 - b2x * s1) * sc);
        qf[qs][3][jx] = (short)f2b((b2x * c1 + b1 * s1) * sc);
      }
    }

    f32x4 of[2][8];
#pragma unroll
    for (int qs = 0; qs < 2; ++qs)
#pragma unroll
      for (int i = 0; i < 8; ++i) of[qs][i] = (f32x4){0.f, 0.f, 0.f, 0.f};
    float mrow[2] = {-3.0e38f, -3.0e38f};
    float lrow[2] = {0.f, 0.f};

    const int nsteps = 2 * qt + 2;       // 64-key steps covering q0+128 keys

    // ---- prologue: stage tile 0 into Ks[0]
#pragma unroll
    for (int i = 0; i < 4; ++i) {
      int c = i * 256 + tid;
      int key = c >> 4;
      int ch = (c & 15) ^ (key & 7);
      gload_lds16(Kp + (size_t)key * KV2 + ch * 8, &Ks[0][0] + c * 8);
    }
    __syncthreads();   // tile 0 visible

#pragma unroll 1
    for (int t = 0; t < nsteps; ++t) {
      const int kv0 = t << 6;
      const unsigned short* Kcur = &Ks[t & 1][0];

      // --- V group-0 loads FIRST (PV0 waits only these; prefetch stays in flight)
      bf16x8 vf[8];
#pragma unroll
      for (int dc2 = 0; dc2 < 8; ++dc2)
        vf[dc2] = *reinterpret_cast<const bf16x8*>(
            Vtp + (size_t)(dc2 * 16 + lr) * S_LEN + kv0 + kb * 8);

      // --- prefetch next K tile (drained only at step-end barrier)
      if (t + 1 < nsteps) {
        unsigned short* Knxt = &Ks[(t + 1) & 1][0];
#pragma unroll
        for (int i = 0; i < 4; ++i) {
          int c = i * 256 + tid;
          int key = c >> 4;
          int ch = (c & 15) ^ (key & 7);
          gload_lds16(Kp + (size_t)(kv0 + 64 + key) * KV2 + ch * 8, Knxt + c * 8);
        }
      }

      // --- S^T = K Q^T : kf shared across q-sets
      f32x4 sf[2][4];
#pragma unroll
      for (int qs = 0; qs < 2; ++qs)
#pragma unroll
        for (int ki = 0; ki < 4; ++ki) sf[qs][ki] = (f32x4){0.f, 0.f, 0.f, 0.f};
#pragma unroll
      for (int ki = 0; ki < 4; ++ki)
#pragma unroll
        for (int dc = 0; dc < 4; ++dc) {
          bf16x8 kf = *reinterpret_cast<const bf16x8*>(
              Kcur + (ki * 16 + lr) * 128 + (((dc * 4 + kb) ^ (lr & 7)) << 3));
          sf[0][ki] = __builtin_amdgcn_mfma_f32_16x16x32_bf16(kf, qf[0][dc], sf[0][ki], 0, 0, 0);
          sf[1][ki] = __builtin_amdgcn_mfma_f32_16x16x32_bf16(kf, qf[1][dc], sf[1][ki], 0, 0, 0);
        }

      // --- causal mask per q-set (wave-uniform skip)
#pragma unroll
      for (int qs = 0; qs < 2; ++qs) {
        if (kv0 + 63 > q0 + wave * 32 + qs * 16) {
          const int thr = qrowQ[qs] - kv0;
#pragma unroll
          for (int ki = 0; ki < 4; ++ki)
#pragma unroll
            for (int r = 0; r < 4; ++r)
              if (ki * 16 + kb * 4 + r > thr) sf[qs][ki][r] = -3.0e38f;
        }
      }

      // --- two independent softmax chains (log2 domain), defer-max THR=11.5 bits
#pragma unroll
      for (int qs = 0; qs < 2; ++qs) {
        float m8 = -3.0e38f;
#pragma unroll
        for (int ki = 0; ki < 4; ++ki)
#pragma unroll
          for (int r = 0; r < 4; ++r) m8 = fmaxf(m8, sf[qs][ki][r]);
        m8 = fmaxf(m8, __shfl_xor(m8, 16));
        m8 = fmaxf(m8, __shfl_xor(m8, 32));
        if (__any(m8 > mrow[qs] + 11.5f)) {
          float mn = fmaxf(mrow[qs], m8);
          float corr = exp2fast(mrow[qs] - mn);
          lrow[qs] *= corr;
#pragma unroll
          for (int r = 0; r < 4; ++r) {
            float cr = __shfl(corr, kb * 4 + r);
#pragma unroll
            for (int dc2 = 0; dc2 < 8; ++dc2) of[qs][dc2][r] *= cr;
          }
          mrow[qs] = mn;
        }
        float rs = 0.f;
#pragma unroll
        for (int ki = 0; ki < 4; ++ki) {
          float p0 = exp2fast(sf[qs][ki][0] - mrow[qs]);   // bounded by 2^11.5
          float p1 = exp2fast(sf[qs][ki][1] - mrow[qs]);
          float p2 = exp2fast(sf[qs][ki][2] - mrow[qs]);
          float p3 = exp2fast(sf[qs][ki][3] - mrow[qs]);
          rs += (p0 + p1) + (p2 + p3);
          uint2 w;
          w.x = cvtpk(p0, p1);
          w.y = cvtpk(p2, p3);
          *reinterpret_cast<uint2*>(&Ps[wave][qs][lr * 72 + ki * 16 + kb * 4]) = w;
        }
        rs += __shfl_xor(rs, 16);
        rs += __shfl_xor(rs, 32);
        lrow[qs] += rs;
      }
      asm volatile("s_waitcnt lgkmcnt(0)" ::: "memory");
      __builtin_amdgcn_sched_barrier(0);

      // --- PV group 0 (keys kv0..+31), both q-sets share vf
      {
        bf16x8 pf0 = *reinterpret_cast<const bf16x8*>(&Ps[wave][0][lr * 72 + kb * 8]);
        bf16x8 pf1 = *reinterpret_cast<const bf16x8*>(&Ps[wave][1][lr * 72 + kb * 8]);
#pragma unroll
        for (int dc2 = 0; dc2 < 8; ++dc2) {
          of[0][dc2] = __builtin_amdgcn_mfma_f32_16x16x32_bf16(pf0, vf[dc2], of[0][dc2], 0, 0, 0);
          of[1][dc2] = __builtin_amdgcn_mfma_f32_16x16x32_bf16(pf1, vf[dc2], of[1][dc2], 0, 0, 0);
        }
      }
      // --- V group 1 + PV group 1
#pragma unroll
      for (int dc2 = 0; dc2 < 8; ++dc2)
        vf[dc2] = *reinterpret_cast<const bf16x8*>(
            Vtp + (size_t)(dc2 * 16 + lr) * S_LEN + kv0 + 32 + kb * 8);
      {
        bf16x8 pf0 = *reinterpret_cast<const bf16x8*>(&Ps[wave][0][lr * 72 + 32 + kb * 8]);
        bf16x8 pf1 = *reinterpret_cast<const bf16x8*>(&Ps[wave][1][lr * 72 + 32 + kb * 8]);
#pragma unroll
        for (int dc2 = 0; dc2 < 8; ++dc2) {
          of[0][dc2] = __builtin_amdgcn_mfma_f32_16x16x32_bf16(pf0, vf[dc2], of[0][dc2], 0, 0, 0);
          of[1][dc2] = __builtin_amdgcn_mfma_f32_16x16x32_bf16(pf1, vf[dc2], of[1][dc2], 0, 0, 0);
        }
      }

      __syncthreads();  // one drain/step: prefetch resident; all Kcur reads done
    }

    // --- normalize + write (of[qs] row q = kb*4+r; lrow lives at lane lr = q)
#pragma unroll
    for (int qs = 0; qs < 2; ++qs) {
      float linv[4];
#pragma unroll
      for (int r = 0; r < 4; ++r) linv[r] = 1.0f / __shfl(lrow[qs], kb * 4 + r);
#pragma unroll
      for (int dc2 = 0; dc2 < 8; ++dc2)
#pragma unroll
        for (int r = 0; r < 4; ++r) {
          int qg = q0 + wave * 32 + qs * 16 + kb * 4 + r;
          Op[(size_t)qg * HID_DIM + dc2 * 16 + lr] = f2b(of[qs][dc2][r] * linv[r]);
        }
    }
  }
}

// ---------------- launch ----------------
extern "C" void kernel_launch(void* const* d_in, const int* in_sizes, int n_in,
                              void* d_out, int out_size, void* d_ws, size_t ws_size,
                              hipStream_t stream) {
  const float* x  = (const float*)d_in[0];
  const float* Wq = (const float*)d_in[2];
  const float* Wk = (const float*)d_in[3];
  const float* Wv = (const float*)d_in[4];
  const float* Wo = (const float*)d_in[5];
  float* out = (float*)d_out;

  char* ws = (char*)d_ws;
  unsigned short* xb  = (unsigned short*)(ws + 0);          // 33.5MB (later reused as AO)
  unsigned short* wtb = (unsigned short*)(ws + 33554432);   // Wq^T; later Wo^T
  unsigned short* wkt = (unsigned short*)(ws + 67108864);   // Wk^T | Wv^T contiguous; later Vt
  unsigned short* wvt = (unsigned short*)(ws + 75497472);
  unsigned short* Qb  = (unsigned short*)(ws + 83886080);
  unsigned short* KVb = (unsigned short*)(ws + 117440512);  // [4096][2048] fused K|V
  float* cosT = (float*)(ws + 134217728);
  float* sinT = (float*)(ws + 134742016);
  unsigned short* AO  = xb;   // alias: x dead after KV projection
  unsigned short* Vtb = wkt;  // alias: Wk^T/Wv^T dead after KV projection
  unsigned short* woT = wtb;  // alias: Wq^T dead after Q projection

  prep_k<<<41472, 256, 0, stream>>>(x, xb, Wq, wtb, Wk, wkt, Wv, wvt, cosT, sinT);

  gemm256<unsigned short><<<256, 512, 0, stream>>>(xb, wtb, Qb, BS_ROWS, HID_DIM, HID_DIM);  // raw Q
  gemm_bt<unsigned short><<<512, 256, 0, stream>>>(xb, wkt, KVb, BS_ROWS, KV2, HID_DIM);     // fused K|V

  // K-RoPE + V transpose + Wo transpose (wkt/wtb regions now dead -> Vt/woT)
  postkv_k<<<22528, 256, 0, stream>>>(KVb, Vtb, Wo, woT, cosT, sinT);

  attn_fwd<<<dim3(8, 64), 256, 0, stream>>>(Qb, KVb, Vtb, cosT, sinT, AO);

  gemm256<float><<<256, 512, 0, stream>>>(AO, woT, out, BS_ROWS, HID_DIM, HID_DIM);
}